// Round 3
// baseline (67.560 us; speedup 1.0000x reference)
//
#include <hip/hip_runtime.h>
#include <hip/hip_bf16.h>
#include <math.h>

#define SOM_M 256
#define SOM_N 256
#define SOM_DIM 512
#define NROWS (SOM_M * SOM_N)

#define GRID 1024
#define BLOCK 256
#define ROWS_PER_BLOCK (NROWS / GRID)               // 64
#define F4_PER_ROW (SOM_DIM / 4)                    // 128
#define F4_PER_BLOCK (ROWS_PER_BLOCK * F4_PER_ROW)  // 8192
#define UPD_ITERS (F4_PER_BLOCK / BLOCK)            // 32

static __device__ __forceinline__ unsigned long long umin64(unsigned long long a,
                                                            unsigned long long b) {
    return a < b ? a : b;
}

// ---- Kernel 1: per-row squared L2 distance, per-block packed argmin partial.
// Block b owns rows [b*64, b*64+64); wave w handles 16 consecutive rows.
__global__ __launch_bounds__(BLOCK) void som_dist(
    const float* __restrict__ x, const float* __restrict__ w,
    unsigned long long* __restrict__ ws) {
    __shared__ float xs[SOM_DIM];
    for (int j = threadIdx.x; j < SOM_DIM; j += BLOCK) xs[j] = x[j];
    __syncthreads();

    const int wave = threadIdx.x >> 6;
    const int lane = threadIdx.x & 63;
    const float4* xs4 = (const float4*)xs;
    const float4 xa = xs4[lane];
    const float4 xb = xs4[lane + 64];

    float best = INFINITY;
    int bidx = 0;
    const int row0 = blockIdx.x * ROWS_PER_BLOCK + wave * 16;
    #pragma unroll 2
    for (int k = 0; k < 16; ++k) {
        const int row = row0 + k;
        const float4* wr = (const float4*)(w + (size_t)row * SOM_DIM);
        float4 a = wr[lane];
        float4 b = wr[lane + 64];
        float t, d = 0.0f;
        t = a.x - xa.x; d += t * t;
        t = a.y - xa.y; d += t * t;
        t = a.z - xa.z; d += t * t;
        t = a.w - xa.w; d += t * t;
        t = b.x - xb.x; d += t * t;
        t = b.y - xb.y; d += t * t;
        t = b.z - xb.z; d += t * t;
        t = b.w - xb.w; d += t * t;
        #pragma unroll
        for (int s = 1; s < 64; s <<= 1) d += __shfl_xor(d, s);
        if (d < best) { best = d; bidx = row; }  // rows increasing -> first-min kept
    }

    __shared__ unsigned long long sm[4];
    if (lane == 0)
        sm[wave] = ((unsigned long long)__float_as_uint(best) << 32) | (unsigned)bidx;
    __syncthreads();
    if (threadIdx.x == 0) {
        unsigned long long m = sm[0];
        #pragma unroll
        for (int k = 1; k < 4; ++k) m = umin64(m, sm[k]);
        ws[blockIdx.x] = m;  // u64-min over these == (min dist, then min row)
    }
}

// ---- Kernel 2: redundant 1024-partial reduce (cheap, L2/L3-hot), then update.
__global__ __launch_bounds__(BLOCK) void som_update(
    const float* __restrict__ x, const float* __restrict__ w,
    const int* __restrict__ it_ptr, const unsigned long long* __restrict__ ws,
    float* __restrict__ out) {
    __shared__ float xs[SOM_DIM];
    __shared__ unsigned long long red[4];
    __shared__ float lrs[ROWS_PER_BLOCK];

    for (int j = threadIdx.x; j < SOM_DIM; j += BLOCK) xs[j] = x[j];

    // Reduce the 1024 packed partials (visible via kernel dispatch boundary).
    unsigned long long m = ws[threadIdx.x];
    m = umin64(m, ws[threadIdx.x + 256]);
    m = umin64(m, ws[threadIdx.x + 512]);
    m = umin64(m, ws[threadIdx.x + 768]);
    #pragma unroll
    for (int s = 1; s < 64; s <<= 1) m = umin64(m, __shfl_xor(m, s));
    const int wave = threadIdx.x >> 6;
    const int lane = threadIdx.x & 63;
    if (lane == 0) red[wave] = m;
    __syncthreads();
    if (threadIdx.x == 0) {
        red[0] = umin64(umin64(red[0], red[1]), umin64(red[2], red[3]));
    }
    __syncthreads();
    const int bmu = (int)(red[0] & 0xFFFFFFFFull);

    // lr table for this block's 64 rows.
    const float lr_decay = 1.0f - (float)(*it_ptr) * 0.01f;
    const float alpha_op = 0.3f * lr_decay;
    const float radius_op = 128.0f * lr_decay;
    const float inv2r2 = 1.0f / (2.0f * radius_op * radius_op);
    if (threadIdx.x < ROWS_PER_BLOCK) {
        const int row = blockIdx.x * ROWS_PER_BLOCK + threadIdx.x;
        const float dr = (float)((bmu >> 8) - (row >> 8));
        const float dc = (float)((bmu & 255) - (row & 255));
        lrs[threadIdx.x] = alpha_op * expf(-(dr * dr + dc * dc) * inv2r2);
    }
    __syncthreads();

    // out = w + lr*(x - w) over this block's 64 rows (same rows as kernel 1).
    const float4* xs4 = (const float4*)xs;
    const float4 xv = xs4[threadIdx.x & (F4_PER_ROW - 1)];
    const size_t base = (size_t)blockIdx.x * F4_PER_BLOCK;
    const int rsub = threadIdx.x >> 7;  // which of the 2 rows covered per iter
    #pragma unroll 4
    for (int i = 0; i < UPD_ITERS; ++i) {
        const size_t idx = base + (size_t)i * BLOCK + threadIdx.x;
        const float lr = lrs[i * 2 + rsub];
        const float4 wv = ((const float4*)w)[idx];
        float4 o;
        o.x = wv.x + lr * (xv.x - wv.x);
        o.y = wv.y + lr * (xv.y - wv.y);
        o.z = wv.z + lr * (xv.z - wv.z);
        o.w = wv.w + lr * (xv.w - wv.w);
        ((float4*)out)[idx] = o;
    }
}

extern "C" void kernel_launch(void* const* d_in, const int* in_sizes, int n_in,
                              void* d_out, int out_size, void* d_ws, size_t ws_size,
                              hipStream_t stream) {
    const float* x = (const float*)d_in[0];
    const float* w = (const float*)d_in[1];
    const int* it  = (const int*)d_in[2];
    float* out = (float*)d_out;
    unsigned long long* ws = (unsigned long long*)d_ws;

    som_dist<<<GRID, BLOCK, 0, stream>>>(x, w, ws);
    som_update<<<GRID, BLOCK, 0, stream>>>(x, w, it, ws, out);
}

// Round 5
// 67.442 us; speedup vs baseline: 1.0017x; 1.0017x over previous
//
#include <hip/hip_runtime.h>
#include <hip/hip_bf16.h>
#include <math.h>

#define SOM_M 256
#define SOM_N 256
#define SOM_DIM 512
#define NROWS (SOM_M * SOM_N)

#define GRID 1024
#define BLOCK 256
#define ROWS_PER_BLOCK (NROWS / GRID)               // 64
#define F4_PER_ROW (SOM_DIM / 4)                    // 128
#define F4_PER_BLOCK (ROWS_PER_BLOCK * F4_PER_ROW)  // 8192
#define UPD_ITERS (F4_PER_BLOCK / BLOCK)            // 32

typedef float v4f __attribute__((ext_vector_type(4)));  // native vector: NT-store ok

static __device__ __forceinline__ unsigned long long umin64(unsigned long long a,
                                                            unsigned long long b) {
    return a < b ? a : b;
}

// ---- Kernel 1: per-row squared L2 distance, per-block packed argmin partial.
// Block b owns rows [b*64, b*64+64); wave w handles 16 consecutive rows.
// Software-pipelined: row k+1's loads issue before row k's reduce chain.
__global__ __launch_bounds__(BLOCK) void som_dist(
    const float* __restrict__ x, const float* __restrict__ w,
    unsigned long long* __restrict__ ws) {
    __shared__ float xs[SOM_DIM];
    for (int j = threadIdx.x; j < SOM_DIM; j += BLOCK) xs[j] = x[j];
    __syncthreads();

    const int wave = threadIdx.x >> 6;
    const int lane = threadIdx.x & 63;
    const float4* xs4 = (const float4*)xs;
    const float4 xa = xs4[lane];
    const float4 xb = xs4[lane + 64];

    float best = INFINITY;
    int bidx = 0;
    const int row0 = blockIdx.x * ROWS_PER_BLOCK + wave * 16;

    const float4* wr = (const float4*)(w + (size_t)row0 * SOM_DIM);
    float4 a = wr[lane];
    float4 b = wr[lane + 64];
    #pragma unroll
    for (int k = 0; k < 16; ++k) {
        float4 na, nb;
        if (k < 15) {
            const float4* wn = (const float4*)(w + (size_t)(row0 + k + 1) * SOM_DIM);
            na = wn[lane];
            nb = wn[lane + 64];
        }
        float t, d = 0.0f;
        t = a.x - xa.x; d += t * t;
        t = a.y - xa.y; d += t * t;
        t = a.z - xa.z; d += t * t;
        t = a.w - xa.w; d += t * t;
        t = b.x - xb.x; d += t * t;
        t = b.y - xb.y; d += t * t;
        t = b.z - xb.z; d += t * t;
        t = b.w - xb.w; d += t * t;
        #pragma unroll
        for (int s = 1; s < 64; s <<= 1) d += __shfl_xor(d, s);
        if (d < best) { best = d; bidx = row0 + k; }  // increasing -> first-min
        a = na; b = nb;
    }

    __shared__ unsigned long long sm[4];
    if (lane == 0)
        sm[wave] = ((unsigned long long)__float_as_uint(best) << 32) | (unsigned)bidx;
    __syncthreads();
    if (threadIdx.x == 0) {
        unsigned long long m = sm[0];
        #pragma unroll
        for (int k = 1; k < 4; ++k) m = umin64(m, sm[k]);
        ws[blockIdx.x] = m;  // u64-min over these == (min dist, then min row)
    }
}

// ---- Kernel 2: redundant 1024-partial reduce, then update with NT stores.
__global__ __launch_bounds__(BLOCK) void som_update(
    const float* __restrict__ x, const float* __restrict__ w,
    const int* __restrict__ it_ptr, const unsigned long long* __restrict__ ws,
    float* __restrict__ out) {
    __shared__ float xs[SOM_DIM];
    __shared__ unsigned long long red[4];
    __shared__ float lrs[ROWS_PER_BLOCK];

    for (int j = threadIdx.x; j < SOM_DIM; j += BLOCK) xs[j] = x[j];

    // Reduce the 1024 packed partials (visible via kernel dispatch boundary).
    unsigned long long m = ws[threadIdx.x];
    m = umin64(m, ws[threadIdx.x + 256]);
    m = umin64(m, ws[threadIdx.x + 512]);
    m = umin64(m, ws[threadIdx.x + 768]);
    #pragma unroll
    for (int s = 1; s < 64; s <<= 1) m = umin64(m, __shfl_xor(m, s));
    const int wave = threadIdx.x >> 6;
    const int lane = threadIdx.x & 63;
    if (lane == 0) red[wave] = m;
    __syncthreads();
    if (threadIdx.x == 0) {
        red[0] = umin64(umin64(red[0], red[1]), umin64(red[2], red[3]));
    }
    __syncthreads();
    const int bmu = (int)(red[0] & 0xFFFFFFFFull);

    // lr table for this block's 64 rows.
    const float lr_decay = 1.0f - (float)(*it_ptr) * 0.01f;
    const float alpha_op = 0.3f * lr_decay;
    const float radius_op = 128.0f * lr_decay;
    const float inv2r2 = 1.0f / (2.0f * radius_op * radius_op);
    if (threadIdx.x < ROWS_PER_BLOCK) {
        const int row = blockIdx.x * ROWS_PER_BLOCK + threadIdx.x;
        const float dr = (float)((bmu >> 8) - (row >> 8));
        const float dc = (float)((bmu & 255) - (row & 255));
        lrs[threadIdx.x] = alpha_op * expf(-(dr * dr + dc * dc) * inv2r2);
    }
    __syncthreads();

    // out = w + lr*(x - w). w-read should hit Infinity Cache (streamed by
    // kernel 1); NT stores keep out-writes from evicting w from L3.
    const float4* xs4 = (const float4*)xs;
    const float4 xv = xs4[threadIdx.x & (F4_PER_ROW - 1)];
    const size_t base = (size_t)blockIdx.x * F4_PER_BLOCK;
    const int rsub = threadIdx.x >> 7;  // which of the 2 rows covered per iter
    #pragma unroll 4
    for (int i = 0; i < UPD_ITERS; ++i) {
        const size_t idx = base + (size_t)i * BLOCK + threadIdx.x;
        const float lr = lrs[i * 2 + rsub];
        const float4 wv = ((const float4*)w)[idx];
        v4f o;
        o.x = wv.x + lr * (xv.x - wv.x);
        o.y = wv.y + lr * (xv.y - wv.y);
        o.z = wv.z + lr * (xv.z - wv.z);
        o.w = wv.w + lr * (xv.w - wv.w);
        __builtin_nontemporal_store(o, (v4f*)out + idx);
    }
}

extern "C" void kernel_launch(void* const* d_in, const int* in_sizes, int n_in,
                              void* d_out, int out_size, void* d_ws, size_t ws_size,
                              hipStream_t stream) {
    const float* x = (const float*)d_in[0];
    const float* w = (const float*)d_in[1];
    const int* it  = (const int*)d_in[2];
    float* out = (float*)d_out;
    unsigned long long* ws = (unsigned long long*)d_ws;

    som_dist<<<GRID, BLOCK, 0, stream>>>(x, w, ws);
    som_update<<<GRID, BLOCK, 0, stream>>>(x, w, it, ws, out);
}

// Round 6
// 65.823 us; speedup vs baseline: 1.0264x; 1.0246x over previous
//
#include <hip/hip_runtime.h>
#include <hip/hip_bf16.h>
#include <math.h>

#define SOM_M 256
#define SOM_N 256
#define SOM_DIM 512
#define NROWS (SOM_M * SOM_N)
#define F4_PER_ROW (SOM_DIM / 4)                    // 128

// ---- dist kernel geometry (proven R1-R5) ----
#define GRID 1024
#define BLOCK 256
#define ROWS_PER_BLOCK (NROWS / GRID)               // 64

// ---- update kernel geometry ----
#define UGRID 2048
#define UBLOCK 256
#define UROWS (NROWS / UGRID)                       // 32
#define UF4 (UROWS * F4_PER_ROW)                    // 4096 float4 per block
#define UITERS (UF4 / UBLOCK)                       // 16
#define UGROUPS (UITERS / 4)                        // 4 groups of 4

typedef float v4f __attribute__((ext_vector_type(4)));

static __device__ __forceinline__ unsigned long long umin64(unsigned long long a,
                                                            unsigned long long b) {
    return a < b ? a : b;
}

// ---- Kernel 1: per-row squared L2 distance, per-block packed argmin partial.
__global__ __launch_bounds__(BLOCK) void som_dist(
    const float* __restrict__ x, const float* __restrict__ w,
    unsigned long long* __restrict__ ws) {
    __shared__ float xs[SOM_DIM];
    for (int j = threadIdx.x; j < SOM_DIM; j += BLOCK) xs[j] = x[j];
    __syncthreads();

    const int wave = threadIdx.x >> 6;
    const int lane = threadIdx.x & 63;
    const float4* xs4 = (const float4*)xs;
    const float4 xa = xs4[lane];
    const float4 xb = xs4[lane + 64];

    float best = INFINITY;
    int bidx = 0;
    const int row0 = blockIdx.x * ROWS_PER_BLOCK + wave * 16;

    const float4* wr = (const float4*)(w + (size_t)row0 * SOM_DIM);
    float4 a = wr[lane];
    float4 b = wr[lane + 64];
    #pragma unroll
    for (int k = 0; k < 16; ++k) {
        float4 na, nb;
        if (k < 15) {
            const float4* wn = (const float4*)(w + (size_t)(row0 + k + 1) * SOM_DIM);
            na = wn[lane];
            nb = wn[lane + 64];
        }
        float t, d = 0.0f;
        t = a.x - xa.x; d += t * t;
        t = a.y - xa.y; d += t * t;
        t = a.z - xa.z; d += t * t;
        t = a.w - xa.w; d += t * t;
        t = b.x - xb.x; d += t * t;
        t = b.y - xb.y; d += t * t;
        t = b.z - xb.z; d += t * t;
        t = b.w - xb.w; d += t * t;
        #pragma unroll
        for (int s = 1; s < 64; s <<= 1) d += __shfl_xor(d, s);
        if (d < best) { best = d; bidx = row0 + k; }  // increasing -> first-min
        a = na; b = nb;
    }

    __shared__ unsigned long long sm[4];
    if (lane == 0)
        sm[wave] = ((unsigned long long)__float_as_uint(best) << 32) | (unsigned)bidx;
    __syncthreads();
    if (threadIdx.x == 0) {
        unsigned long long m = sm[0];
        #pragma unroll
        for (int k = 1; k < 4; ++k) m = umin64(m, sm[k]);
        ws[blockIdx.x] = m;  // u64-min over these == (min dist, then min row)
    }
}

// ---- Kernel 2: prefetch w, reduce partials under the loads, then stream.
__global__ __launch_bounds__(UBLOCK) void som_update(
    const float* __restrict__ x, const float* __restrict__ w,
    const int* __restrict__ it_ptr, const unsigned long long* __restrict__ ws,
    float* __restrict__ out) {
    const int tid = threadIdx.x;
    const size_t base = (size_t)blockIdx.x * UF4;
    const v4f* wv = (const v4f*)w + base;
    v4f* ov = (v4f*)out + base;

    // xv is the same for this thread in every iteration: (i*256+tid)&127 == tid&127.
    const v4f xv = ((const v4f*)x)[tid & (F4_PER_ROW - 1)];

    // Issue group-0 w loads NOW; the ws-reduce below hides their latency.
    v4f c0 = wv[tid];
    v4f c1 = wv[tid + 256];
    v4f c2 = wv[tid + 512];
    v4f c3 = wv[tid + 768];

    // Reduce the 1024 packed partials (L2-hot; visible via dispatch boundary).
    __shared__ unsigned long long red[4];
    unsigned long long m = ws[tid];
    m = umin64(m, ws[tid + 256]);
    m = umin64(m, ws[tid + 512]);
    m = umin64(m, ws[tid + 768]);
    #pragma unroll
    for (int s = 1; s < 64; s <<= 1) m = umin64(m, __shfl_xor(m, s));
    const int wave = tid >> 6;
    const int lane = tid & 63;
    if (lane == 0) red[wave] = m;
    __syncthreads();
    if (tid == 0)
        red[0] = umin64(umin64(red[0], red[1]), umin64(red[2], red[3]));
    __syncthreads();
    const int bmu = (int)(red[0] & 0xFFFFFFFFull);

    // lr table for this block's 32 rows.
    const float lr_decay = 1.0f - (float)(*it_ptr) * 0.01f;
    const float alpha_op = 0.3f * lr_decay;
    const float radius_op = 128.0f * lr_decay;
    const float inv2r2 = 1.0f / (2.0f * radius_op * radius_op);
    __shared__ float lrs[UROWS];
    if (tid < UROWS) {
        const int row = blockIdx.x * UROWS + tid;
        const float dr = (float)((bmu >> 8) - (row >> 8));
        const float dc = (float)((bmu & 255) - (row & 255));
        lrs[tid] = alpha_op * __expf(-(dr * dr + dc * dc) * inv2r2);
    }
    __syncthreads();

    // 4-deep ping-pong pipeline over 4 groups of 4 float4 iterations.
    const int rsub = tid >> 7;  // which of the 2 rows this thread covers per iter
    #pragma unroll
    for (int g = 0; g < UGROUPS; ++g) {
        v4f n0, n1, n2, n3;
        if (g < UGROUPS - 1) {
            const int nb = (g + 1) * 4 * UBLOCK + tid;
            n0 = wv[nb];
            n1 = wv[nb + 256];
            n2 = wv[nb + 512];
            n3 = wv[nb + 768];
        }
        const int i0 = g * 4;  // compile-time per unrolled body
        const float l0 = lrs[(i0 + 0) * 2 + rsub];
        const float l1 = lrs[(i0 + 1) * 2 + rsub];
        const float l2 = lrs[(i0 + 2) * 2 + rsub];
        const float l3 = lrs[(i0 + 3) * 2 + rsub];
        v4f o0 = c0 + l0 * (xv - c0);
        v4f o1 = c1 + l1 * (xv - c1);
        v4f o2 = c2 + l2 * (xv - c2);
        v4f o3 = c3 + l3 * (xv - c3);
        const int ob = i0 * UBLOCK + tid;
        __builtin_nontemporal_store(o0, ov + ob);
        __builtin_nontemporal_store(o1, ov + ob + 256);
        __builtin_nontemporal_store(o2, ov + ob + 512);
        __builtin_nontemporal_store(o3, ov + ob + 768);
        c0 = n0; c1 = n1; c2 = n2; c3 = n3;
    }
}

extern "C" void kernel_launch(void* const* d_in, const int* in_sizes, int n_in,
                              void* d_out, int out_size, void* d_ws, size_t ws_size,
                              hipStream_t stream) {
    const float* x = (const float*)d_in[0];
    const float* w = (const float*)d_in[1];
    const int* it  = (const int*)d_in[2];
    float* out = (float*)d_out;
    unsigned long long* ws = (unsigned long long*)d_ws;

    som_dist<<<GRID, BLOCK, 0, stream>>>(x, w, ws);
    som_update<<<UGRID, UBLOCK, 0, stream>>>(x, w, it, ws, out);
}